// Round 1
// baseline (238.887 us; speedup 1.0000x reference)
//
#include <hip/hip_runtime.h>
#include <hip/hip_bf16.h>
#include <stdint.h>

typedef __bf16 bf16x8 __attribute__((ext_vector_type(8)));
typedef float floatx4 __attribute__((ext_vector_type(4)));

#define B_ 2
#define L_ 4096
#define C_ 1024
#define H_ 16
#define D_ 64
constexpr size_t TEN = (size_t)B_ * H_ * L_ * D_;  // 8388608 elems per q/k/v tensor

__device__ __forceinline__ float bf2f(unsigned short u) {
  union { unsigned int i; float f; } x; x.i = ((unsigned int)u) << 16; return x.f;
}
__device__ __forceinline__ unsigned short f2bf(float f) {
  union { float f; unsigned int i; } x; x.f = f;
  unsigned int i = x.i;
  return (unsigned short)((i + 0x7FFFu + ((i >> 16) & 1u)) >> 16);
}

// direct global->LDS async copy, 16B per lane (global_load_lds_dwordx4)
__device__ __forceinline__ void async_copy16(const unsigned short* g, unsigned short* l) {
  __builtin_amdgcn_global_load_lds(
      (const __attribute__((address_space(1))) unsigned int*)g,
      (__attribute__((address_space(3))) unsigned int*)l,
      16, 0, 0);
}

// ---------------- elementwise f32 -> bf16 ----------------
__global__ __launch_bounds__(256) void cvt_f32_bf16_kernel(
    const float* __restrict__ in, unsigned short* __restrict__ out, int n) {
  int i = (blockIdx.x * 256 + threadIdx.x) * 8;
  if (i >= n) return;
  float4 a = *(const float4*)&in[i];
  float4 b = *(const float4*)&in[i + 4];
  union { uint4 u; unsigned short s[8]; } st;
  st.s[0] = f2bf(a.x); st.s[1] = f2bf(a.y); st.s[2] = f2bf(a.z); st.s[3] = f2bf(a.w);
  st.s[4] = f2bf(b.x); st.s[5] = f2bf(b.y); st.s[6] = f2bf(b.z); st.s[7] = f2bf(b.w);
  *(uint4*)&out[i] = st.u;
}

// ---------------- transpose f32 in -> bf16 out, dims divisible by 64 ----------------
// in: R x Ccols (f32); out: Ccols x R (bf16)
__global__ __launch_bounds__(256) void transpose_f32_bf16(
    const float* __restrict__ in, unsigned short* __restrict__ out,
    int R, int Ccols) {
  __shared__ float tile[64][65];
  const int bx = blockIdx.x * 64;  // col base in input
  const int by = blockIdx.y * 64;  // row base in input
  const int t = threadIdx.x;
  for (int i = t; i < 1024; i += 256) {
    int r = i >> 4, c4 = (i & 15) << 2;
    float4 v = *(const float4*)&in[(size_t)(by + r) * Ccols + bx + c4];
    tile[r][c4] = v.x; tile[r][c4 + 1] = v.y; tile[r][c4 + 2] = v.z; tile[r][c4 + 3] = v.w;
  }
  __syncthreads();
  for (int i = t; i < 512; i += 256) {
    int r = i >> 3, c8 = (i & 7) << 3;  // r = output row (input col)
    union { uint4 u; unsigned short s[8]; } st;
    #pragma unroll
    for (int j = 0; j < 8; ++j) st.s[j] = f2bf(tile[c8 + j][r]);
    *(uint4*)&out[(size_t)(bx + r) * R + by + c8] = st.u;
  }
}

// ---------------- GEMM: A (MxK, bf16) * Bt^T (Bt is NxK, bf16), MFMA ----------------
// m97 structure: 128x128 tile, BK=64, 4 waves, global_load_lds width=16, LINEAR LDS
// (global_load_lds destination must be lane-contiguous -> no padding; T2 swizzle is
//  measured NULL on 2-barrier 128^2 loops, so bank conflicts on ds_read are accepted)
// MODE 0: scatter into q/k/v (B,H,L,D) bf16 with bias + q-scale
// MODE 1: plain C = A*B + bias -> out_f (MxN f32)
template <int MODE>
__global__ __launch_bounds__(256) void gemm_bt_kernel(
    const unsigned short* __restrict__ A, const unsigned short* __restrict__ Bt,
    const float* __restrict__ bias, unsigned short* __restrict__ out_bf,
    float* __restrict__ out_f, int M, int N, int K, float qscale) {
  constexpr int BK = 64;
  __shared__ unsigned short a_sh[128 * BK];
  __shared__ unsigned short b_sh[128 * BK];

  const int t = threadIdx.x;
  const int m0 = blockIdx.y * 128;
  const int n0 = blockIdx.x * 128;
  const int wave = t >> 6, lane = t & 63;
  const int wr = wave >> 1, wc = wave & 1;
  const int lm = lane & 15, quad = lane >> 4;

  // staging geometry: element offset (p*256+t)*8, row = off>>6, col = off&63.
  // wave w lanes write LDS bytes [(p*256+w*64)*16 + lane*16, +16) -> lane-contiguous. OK.
  const int soff = t * 8;           // base element offset for p=0
  const int srow = soff >> 6;       // 0..31
  const int scol = soff & 63;       // multiple of 8 elems = 16B aligned

  floatx4 acc[4][4];
  #pragma unroll
  for (int i = 0; i < 4; ++i)
    #pragma unroll
    for (int j = 0; j < 4; ++j) acc[i][j] = (floatx4)0.0f;

  for (int kt = 0; kt < K; kt += BK) {
    #pragma unroll
    for (int p = 0; p < 4; ++p) {
      int r = srow + p * 32;
      int off = r * BK + scol;
      async_copy16(&A[(size_t)(m0 + r) * K + kt + scol], &a_sh[off]);
      async_copy16(&Bt[(size_t)(n0 + r) * K + kt + scol], &b_sh[off]);
    }
    __syncthreads();   // compiler emits s_waitcnt vmcnt(0) before s_barrier
    #pragma unroll
    for (int ks = 0; ks < BK; ks += 32) {
      bf16x8 af[4], bfr[4];
      #pragma unroll
      for (int i = 0; i < 4; ++i)
        af[i] = *(const bf16x8*)&a_sh[(wr * 64 + i * 16 + lm) * BK + ks + quad * 8];
      #pragma unroll
      for (int j = 0; j < 4; ++j)
        bfr[j] = *(const bf16x8*)&b_sh[(wc * 64 + j * 16 + lm) * BK + ks + quad * 8];
      #pragma unroll
      for (int i = 0; i < 4; ++i)
        #pragma unroll
        for (int j = 0; j < 4; ++j)
          acc[i][j] = __builtin_amdgcn_mfma_f32_16x16x32_bf16(af[i], bfr[j], acc[i][j], 0, 0, 0);
    }
    __syncthreads();
  }

  #pragma unroll
  for (int j = 0; j < 4; ++j) {
    int col = n0 + wc * 64 + j * 16 + lm;
    float bv = bias[col];
    if (MODE == 0) {
      int which = col >> 10;
      int rem = col & 1023;
      int h = rem >> 6, d = rem & 63;
      float mul = (which == 0) ? qscale : 1.0f;
      #pragma unroll
      for (int i = 0; i < 4; ++i)
        #pragma unroll
        for (int r = 0; r < 4; ++r) {
          int row = m0 + wr * 64 + i * 16 + quad * 4 + r;
          int b = row >> 12, l = row & (L_ - 1);
          float v = (acc[i][j][r] + bv) * mul;
          out_bf[(size_t)which * TEN + (((size_t)(b * H_ + h) * L_ + l) * D_ + d)] = f2bf(v);
        }
    } else {
      #pragma unroll
      for (int i = 0; i < 4; ++i)
        #pragma unroll
        for (int r = 0; r < 4; ++r) {
          int row = m0 + wr * 64 + i * 16 + quad * 4 + r;
          out_f[(size_t)row * N + col] = acc[i][j][r] + bv;
        }
    }
  }
}

// ---------------- neighborhood attention, online softmax ----------------
constexpr int KKMAX = 63;
constexpr int TL = 128;
constexpr int LDK = 72;

__global__ __launch_bounds__(256) void natt_kernel(
    const unsigned short* __restrict__ qkv,  // q,k,v each TEN elems, (B,H,L,D) bf16
    const float* __restrict__ rpb,           // H x (2kk-1) f32
    const int* __restrict__ knp,
    unsigned short* __restrict__ attn_out) {  // (B*L) x C bf16
  __shared__ unsigned short k_sh[(TL + KKMAX) * LDK];
  __shared__ unsigned short v_sh[(TL + KKMAX) * LDK];
  __shared__ float rpb_sh[2 * KKMAX + 1];

  const int bh = blockIdx.x;
  const int h = bh & (H_ - 1);
  const int b = bh >> 4;
  const int l0 = blockIdx.y * TL;
  const int t = threadIdx.x;

  int kn = knp[0];
  if (kn > 65536 || kn < 0) {  // guard: value stored as float bits
    union { int i; float f; } u; u.i = kn; kn = (int)u.f;
  }
  int rr = 1;
  while ((rr + 1) * (rr + 1) <= kn) ++rr;
  int kk = rr + 1;
  if (kk > KKMAX) kk = KKMAX;

  int base = l0 - kk / 2;
  if (base < 0) base = 0;
  if (base > L_ - kk) base = L_ - kk;
  int nrows = TL + kk;
  if (nrows > L_ - base) nrows = L_ - base;

  const unsigned short* kg = qkv + TEN + (size_t)bh * L_ * D_;
  const unsigned short* vg = qkv + 2 * TEN + (size_t)bh * L_ * D_;

  for (int i = t; i < nrows * 8; i += 256) {
    int row = i >> 3, c8 = (i & 7) << 3;
    uint4 kv = *(const uint4*)&kg[(size_t)(base + row) * D_ + c8];
    *(uint4*)&k_sh[row * LDK + c8] = kv;
    uint4 vv = *(const uint4*)&vg[(size_t)(base + row) * D_ + c8];
    *(uint4*)&v_sh[row * LDK + c8] = vv;
  }
  int nb = 2 * kk - 1;
  for (int i = t; i < nb; i += 256) rpb_sh[i] = rpb[h * nb + i];
  __syncthreads();

  const int qi = t >> 1, half = t & 1;
  const int l = l0 + qi;

  const unsigned short* qg = qkv + (size_t)bh * L_ * D_ + (size_t)l * D_ + half * 32;
  float qv[32];
  #pragma unroll
  for (int c = 0; c < 4; ++c) {
    union { uint4 u; unsigned short s[8]; } ld;
    ld.u = *(const uint4*)&qg[c * 8];
    #pragma unroll
    for (int j = 0; j < 8; ++j) qv[c * 8 + j] = bf2f(ld.s[j]);
  }

  int start = l - kk / 2;
  if (start < 0) start = 0;
  if (start > L_ - kk) start = L_ - kk;
  const int srow = start - base;
  const int boff = start - l + kk - 1;

  float m = -1e30f, lsum = 0.0f;
  float accv[32];
  #pragma unroll
  for (int d = 0; d < 32; ++d) accv[d] = 0.0f;

  for (int j = 0; j < kk; ++j) {
    const unsigned short* kr = &k_sh[(srow + j) * LDK + half * 32];
    float partial = 0.0f;
    #pragma unroll
    for (int c = 0; c < 4; ++c) {
      union { uint4 u; unsigned short s[8]; } ld;
      ld.u = *(const uint4*)&kr[c * 8];
      #pragma unroll
      for (int jj = 0; jj < 8; ++jj) partial += qv[c * 8 + jj] * bf2f(ld.s[jj]);
    }
    float s = partial + __shfl_xor(partial, 1) + rpb_sh[boff + j];
    float p;
    if (s > m) {
      float corr = __expf(m - s);
      lsum *= corr;
      #pragma unroll
      for (int d = 0; d < 32; ++d) accv[d] *= corr;
      m = s;
      p = 1.0f;
    } else {
      p = __expf(s - m);
    }
    lsum += p;
    const unsigned short* vr = &v_sh[(srow + j) * LDK + half * 32];
    #pragma unroll
    for (int c = 0; c < 4; ++c) {
      union { uint4 u; unsigned short s[8]; } ld;
      ld.u = *(const uint4*)&vr[c * 8];
      #pragma unroll
      for (int jj = 0; jj < 8; ++jj) accv[c * 8 + jj] += p * bf2f(ld.s[jj]);
    }
  }
  float inv = 1.0f / lsum;
  unsigned short* og = attn_out + ((size_t)(b * L_ + l) * C_ + h * D_ + half * 32);
  #pragma unroll
  for (int c = 0; c < 4; ++c) {
    union { uint4 u; unsigned short s[8]; } st;
    #pragma unroll
    for (int jj = 0; jj < 8; ++jj) st.s[jj] = f2bf(accv[c * 8 + jj] * inv);
    *(uint4*)&og[c * 8] = st.u;
  }
}

extern "C" void kernel_launch(void* const* d_in, const int* in_sizes, int n_in,
                              void* d_out, int out_size, void* d_ws, size_t ws_size,
                              hipStream_t stream) {
  const float* x      = (const float*)d_in[0];
  const float* w_qkv  = (const float*)d_in[1];
  const float* b_qkv  = (const float*)d_in[2];
  const float* rpb    = (const float*)d_in[3];
  const float* w_proj = (const float*)d_in[4];
  const float* b_proj = (const float*)d_in[5];
  const int* kn       = (const int*)d_in[6];
  float* out          = (float*)d_out;

  unsigned short* ws      = (unsigned short*)d_ws;
  unsigned short* wT_qkv  = ws;                              // 3072x1024 bf16
  unsigned short* wT_proj = wT_qkv + (size_t)3072 * 1024;    // 1024x1024 bf16
  unsigned short* x_bf    = wT_proj + (size_t)1024 * 1024;   // 8192x1024 bf16
  unsigned short* qkv_ws  = x_bf + (size_t)8192 * 1024;      // 3*TEN bf16
  unsigned short* attn_ws = qkv_ws + 3 * TEN;                // 8192x1024 bf16

  cvt_f32_bf16_kernel<<<(8192 * 1024) / (256 * 8), 256, 0, stream>>>(x, x_bf, 8192 * 1024);
  transpose_f32_bf16<<<dim3(3072 / 64, 1024 / 64), 256, 0, stream>>>(w_qkv, wT_qkv, 1024, 3072);
  transpose_f32_bf16<<<dim3(1024 / 64, 1024 / 64), 256, 0, stream>>>(w_proj, wT_proj, 1024, 1024);
  gemm_bt_kernel<0><<<dim3(3072 / 128, 8192 / 128), 256, 0, stream>>>(
      x_bf, wT_qkv, b_qkv, qkv_ws, nullptr, 8192, 3072, 1024, 0.125f);
  natt_kernel<<<dim3(B_ * H_, L_ / TL), 256, 0, stream>>>(qkv_ws, rpb, kn, attn_ws);
  gemm_bt_kernel<1><<<dim3(1024 / 128, 8192 / 128), 256, 0, stream>>>(
      attn_ws, wT_proj, b_proj, nullptr, out, 8192, 1024, 1024, 1.0f);
}

// Round 2
// 232.522 us; speedup vs baseline: 1.0274x; 1.0274x over previous
//
#include <hip/hip_runtime.h>
#include <hip/hip_bf16.h>
#include <stdint.h>

typedef __bf16 bf16x8 __attribute__((ext_vector_type(8)));
typedef float floatx4 __attribute__((ext_vector_type(4)));

#define B_ 2
#define L_ 4096
#define C_ 1024
#define H_ 16
#define D_ 64
constexpr size_t TEN = (size_t)B_ * H_ * L_ * D_;  // 8388608 elems per q/k/v tensor

__device__ __forceinline__ float bf2f(unsigned short u) {
  union { unsigned int i; float f; } x; x.i = ((unsigned int)u) << 16; return x.f;
}
__device__ __forceinline__ unsigned short f2bf(float f) {
  union { float f; unsigned int i; } x; x.f = f;
  unsigned int i = x.i;
  return (unsigned short)((i + 0x7FFFu + ((i >> 16) & 1u)) >> 16);
}

// direct global->LDS async copy, 16B per lane (global_load_lds_dwordx4)
__device__ __forceinline__ void async_copy16(const unsigned short* g, unsigned short* l) {
  __builtin_amdgcn_global_load_lds(
      (const __attribute__((address_space(1))) unsigned int*)g,
      (__attribute__((address_space(3))) unsigned int*)l,
      16, 0, 0);
}

// ---------------- elementwise f32 -> bf16 ----------------
__global__ __launch_bounds__(256) void cvt_f32_bf16_kernel(
    const float* __restrict__ in, unsigned short* __restrict__ out, int n) {
  int i = (blockIdx.x * 256 + threadIdx.x) * 8;
  if (i >= n) return;
  float4 a = *(const float4*)&in[i];
  float4 b = *(const float4*)&in[i + 4];
  union { uint4 u; unsigned short s[8]; } st;
  st.s[0] = f2bf(a.x); st.s[1] = f2bf(a.y); st.s[2] = f2bf(a.z); st.s[3] = f2bf(a.w);
  st.s[4] = f2bf(b.x); st.s[5] = f2bf(b.y); st.s[6] = f2bf(b.z); st.s[7] = f2bf(b.w);
  *(uint4*)&out[i] = st.u;
}

// ---------------- transpose f32 in -> bf16 out, dims divisible by 64 ----------------
__global__ __launch_bounds__(256) void transpose_f32_bf16(
    const float* __restrict__ in, unsigned short* __restrict__ out,
    int R, int Ccols) {
  __shared__ float tile[64][65];
  const int bx = blockIdx.x * 64;  // col base in input
  const int by = blockIdx.y * 64;  // row base in input
  const int t = threadIdx.x;
  for (int i = t; i < 1024; i += 256) {
    int r = i >> 4, c4 = (i & 15) << 2;
    float4 v = *(const float4*)&in[(size_t)(by + r) * Ccols + bx + c4];
    tile[r][c4] = v.x; tile[r][c4 + 1] = v.y; tile[r][c4 + 2] = v.z; tile[r][c4 + 3] = v.w;
  }
  __syncthreads();
  for (int i = t; i < 512; i += 256) {
    int r = i >> 3, c8 = (i & 7) << 3;  // r = output row (input col)
    union { uint4 u; unsigned short s[8]; } st;
    #pragma unroll
    for (int j = 0; j < 8; ++j) st.s[j] = f2bf(tile[c8 + j][r]);
    *(uint4*)&out[(size_t)(bx + r) * R + by + c8] = st.u;
  }
}

// ---------------- GEMM: A (MxK, bf16) * Bt^T (Bt is NxK, bf16), MFMA ----------------
// Deep pipeline: 4 LDS K-tile buffers, counted vmcnt (never 0 in steady state),
// ONE raw s_barrier per K-step, global_load_lds width=16 with rule-#21 XOR swizzle
// (linear LDS dest, inverse-swizzled GLOBAL source col, same XOR on read address).
// K is hard-wired to 1024 (16 tiles of BK=64), both call sites use K=1024.
// MODE 0: scatter into q/k/v (B,H,L,D) bf16 with bias + q-scale
// MODE 1: plain C = A*B + bias -> out_f (MxN f32)
template <int MODE>
__global__ __launch_bounds__(256) void gemm_bt_kernel(
    const unsigned short* __restrict__ A, const unsigned short* __restrict__ Bt,
    const float* __restrict__ bias, unsigned short* __restrict__ out_bf,
    float* __restrict__ out_f, int M, int N, int K, float qscale) {
  constexpr int BK = 64;
  constexpr int TE = 128 * BK;  // 8192 elems = 16 KiB per tile
  // 8 distinct LDS globals -> alias analysis keeps buffers independent (no spurious waits)
  __shared__ unsigned short a_sh0[TE], a_sh1[TE], a_sh2[TE], a_sh3[TE];
  __shared__ unsigned short b_sh0[TE], b_sh1[TE], b_sh2[TE], b_sh3[TE];

  const int t = threadIdx.x;
  // XCD-aware swizzle of flat block id (nwg % 8 == 0 for both launches)
  const int nwgx = gridDim.x;
  const int nwg = nwgx * gridDim.y;
  const int flat = blockIdx.y * nwgx + blockIdx.x;
  const int cpx = nwg >> 3;
  const int swz = (flat & 7) * cpx + (flat >> 3);
  const int m0 = (swz / nwgx) * 128;
  const int n0 = (swz % nwgx) * 128;

  const int wave = t >> 6, lane = t & 63;
  const int wr = wave >> 1, wc = wave & 1;
  const int lm = lane & 15, quad = lane >> 4;

  floatx4 acc[4][4];
  #pragma unroll
  for (int i = 0; i < 4; ++i)
    #pragma unroll
    for (int j = 0; j < 4; ++j) acc[i][j] = (floatx4)0.0f;

// stage one K-tile (A and B halves) = 8 VMEM instr/thread; LDS dest linear,
// global source column XOR-swizzled so that a swizzled READ returns logical data
#define STAGE_TILE(TT, SA, SB) do { \
    int kt_ = (TT) * BK; \
    _Pragma("unroll") \
    for (int p = 0; p < 4; ++p) { \
      int off = (p * 256 + t) * 8; \
      int r_ = off >> 6; \
      int c_ = (off & 63) ^ ((r_ & 7) << 3); \
      async_copy16(&A[(size_t)(m0 + r_) * K + kt_ + c_], &SA[off]); \
      async_copy16(&Bt[(size_t)(n0 + r_) * K + kt_ + c_], &SB[off]); \
    } \
  } while (0)

// one K-step: wait own stages (counted), barrier (all waves' stages landed +
// all waves' previous reads of the stage-target buffer completed), issue
// prefetch of tile TT+3, then ds_read (swizzled) + 32 MFMA.
#define KSTEP(TT, ASH, BSH, SA, SB, DO_ST, VMC) do { \
    asm volatile("s_waitcnt vmcnt(" #VMC ")" ::: "memory"); \
    __builtin_amdgcn_s_barrier(); \
    asm volatile("" ::: "memory"); \
    if (DO_ST) STAGE_TILE((TT) + 3, SA, SB); \
    _Pragma("unroll") \
    for (int ks = 0; ks < BK; ks += 32) { \
      bf16x8 af[4], bfr[4]; \
      _Pragma("unroll") \
      for (int i = 0; i < 4; ++i) { \
        int ra = wr * 64 + i * 16 + lm; \
        af[i] = *(const bf16x8*)&ASH[ra * 64 + ((ks + quad * 8) ^ ((ra & 7) << 3))]; \
      } \
      _Pragma("unroll") \
      for (int j = 0; j < 4; ++j) { \
        int rb = wc * 64 + j * 16 + lm; \
        bfr[j] = *(const bf16x8*)&BSH[rb * 64 + ((ks + quad * 8) ^ ((rb & 7) << 3))]; \
      } \
      _Pragma("unroll") \
      for (int i = 0; i < 4; ++i) \
        _Pragma("unroll") \
        for (int j = 0; j < 4; ++j) \
          acc[i][j] = __builtin_amdgcn_mfma_f32_16x16x32_bf16(af[i], bfr[j], acc[i][j], 0, 0, 0); \
    } \
  } while (0)

  // prologue: stage tiles 0..2 into bufs 0..2 (24 VMEM outstanding)
  STAGE_TILE(0, a_sh0, b_sh0);
  STAGE_TILE(1, a_sh1, b_sh1);
  STAGE_TILE(2, a_sh2, b_sh2);

  // steady state: tiles 0..11, stage target = buf (t+3)&3, vmcnt(16) = 2 tiles in flight
  for (int g = 0; g < 3; ++g) {
    int tb = g * 4;
    KSTEP(tb + 0, a_sh0, b_sh0, a_sh3, b_sh3, true, 16);
    KSTEP(tb + 1, a_sh1, b_sh1, a_sh0, b_sh0, true, 16);
    KSTEP(tb + 2, a_sh2, b_sh2, a_sh1, b_sh1, true, 16);
    KSTEP(tb + 3, a_sh3, b_sh3, a_sh2, b_sh2, true, 16);
  }
  // tail: tiles 12..15 (tile 12 stages tile 15; then drain 16 -> 8 -> 0)
  KSTEP(12, a_sh0, b_sh0, a_sh3, b_sh3, true, 16);
  KSTEP(13, a_sh1, b_sh1, a_sh0, b_sh0, false, 16);
  KSTEP(14, a_sh2, b_sh2, a_sh0, b_sh0, false, 8);
  KSTEP(15, a_sh3, b_sh3, a_sh0, b_sh0, false, 0);

#undef KSTEP
#undef STAGE_TILE

  #pragma unroll
  for (int j = 0; j < 4; ++j) {
    int col = n0 + wc * 64 + j * 16 + lm;
    float bv = bias[col];
    if (MODE == 0) {
      int which = col >> 10;
      int rem = col & 1023;
      int h = rem >> 6, d = rem & 63;
      float mul = (which == 0) ? qscale : 1.0f;
      #pragma unroll
      for (int i = 0; i < 4; ++i)
        #pragma unroll
        for (int r = 0; r < 4; ++r) {
          int row = m0 + wr * 64 + i * 16 + quad * 4 + r;
          int b = row >> 12, l = row & (L_ - 1);
          float v = (acc[i][j][r] + bv) * mul;
          out_bf[(size_t)which * TEN + (((size_t)(b * H_ + h) * L_ + l) * D_ + d)] = f2bf(v);
        }
    } else {
      #pragma unroll
      for (int i = 0; i < 4; ++i)
        #pragma unroll
        for (int r = 0; r < 4; ++r) {
          int row = m0 + wr * 64 + i * 16 + quad * 4 + r;
          out_f[(size_t)row * N + col] = acc[i][j][r] + bv;
        }
    }
  }
}

// ---------------- neighborhood attention, online softmax ----------------
constexpr int KKMAX = 63;
constexpr int TL = 128;
constexpr int LDK = 72;

__global__ __launch_bounds__(256) void natt_kernel(
    const unsigned short* __restrict__ qkv,  // q,k,v each TEN elems, (B,H,L,D) bf16
    const float* __restrict__ rpb,           // H x (2kk-1) f32
    const int* __restrict__ knp,
    unsigned short* __restrict__ attn_out) {  // (B*L) x C bf16
  __shared__ unsigned short k_sh[(TL + KKMAX) * LDK];
  __shared__ unsigned short v_sh[(TL + KKMAX) * LDK];
  __shared__ float rpb_sh[2 * KKMAX + 1];

  const int bh = blockIdx.x;
  const int h = bh & (H_ - 1);
  const int b = bh >> 4;
  const int l0 = blockIdx.y * TL;
  const int t = threadIdx.x;

  int kn = knp[0];
  if (kn > 65536 || kn < 0) {  // guard: value stored as float bits
    union { int i; float f; } u; u.i = kn; kn = (int)u.f;
  }
  int rr = 1;
  while ((rr + 1) * (rr + 1) <= kn) ++rr;
  int kk = rr + 1;
  if (kk > KKMAX) kk = KKMAX;

  int base = l0 - kk / 2;
  if (base < 0) base = 0;
  if (base > L_ - kk) base = L_ - kk;
  int nrows = TL + kk;
  if (nrows > L_ - base) nrows = L_ - base;

  const unsigned short* kg = qkv + TEN + (size_t)bh * L_ * D_;
  const unsigned short* vg = qkv + 2 * TEN + (size_t)bh * L_ * D_;

  for (int i = t; i < nrows * 8; i += 256) {
    int row = i >> 3, c8 = (i & 7) << 3;
    uint4 kv = *(const uint4*)&kg[(size_t)(base + row) * D_ + c8];
    *(uint4*)&k_sh[row * LDK + c8] = kv;
    uint4 vv = *(const uint4*)&vg[(size_t)(base + row) * D_ + c8];
    *(uint4*)&v_sh[row * LDK + c8] = vv;
  }
  int nb = 2 * kk - 1;
  for (int i = t; i < nb; i += 256) rpb_sh[i] = rpb[h * nb + i];
  __syncthreads();

  const int qi = t >> 1, half = t & 1;
  const int l = l0 + qi;

  const unsigned short* qg = qkv + (size_t)bh * L_ * D_ + (size_t)l * D_ + half * 32;
  float qv[32];
  #pragma unroll
  for (int c = 0; c < 4; ++c) {
    union { uint4 u; unsigned short s[8]; } ld;
    ld.u = *(const uint4*)&qg[c * 8];
    #pragma unroll
    for (int j = 0; j < 8; ++j) qv[c * 8 + j] = bf2f(ld.s[j]);
  }

  int start = l - kk / 2;
  if (start < 0) start = 0;
  if (start > L_ - kk) start = L_ - kk;
  const int srow = start - base;
  const int boff = start - l + kk - 1;

  float m = -1e30f, lsum = 0.0f;
  float accv[32];
  #pragma unroll
  for (int d = 0; d < 32; ++d) accv[d] = 0.0f;

  for (int j = 0; j < kk; ++j) {
    const unsigned short* kr = &k_sh[(srow + j) * LDK + half * 32];
    float partial = 0.0f;
    #pragma unroll
    for (int c = 0; c < 4; ++c) {
      union { uint4 u; unsigned short s[8]; } ld;
      ld.u = *(const uint4*)&kr[c * 8];
      #pragma unroll
      for (int jj = 0; jj < 8; ++jj) partial += qv[c * 8 + jj] * bf2f(ld.s[jj]);
    }
    float s = partial + __shfl_xor(partial, 1) + rpb_sh[boff + j];
    float p;
    if (s > m) {
      float corr = __expf(m - s);
      lsum *= corr;
      #pragma unroll
      for (int d = 0; d < 32; ++d) accv[d] *= corr;
      m = s;
      p = 1.0f;
    } else {
      p = __expf(s - m);
    }
    lsum += p;
    const unsigned short* vr = &v_sh[(srow + j) * LDK + half * 32];
    #pragma unroll
    for (int c = 0; c < 4; ++c) {
      union { uint4 u; unsigned short s[8]; } ld;
      ld.u = *(const uint4*)&vr[c * 8];
      #pragma unroll
      for (int jj = 0; jj < 8; ++jj) accv[c * 8 + jj] += p * bf2f(ld.s[jj]);
    }
  }
  float inv = 1.0f / lsum;
  unsigned short* og = attn_out + ((size_t)(b * L_ + l) * C_ + h * D_ + half * 32);
  #pragma unroll
  for (int c = 0; c < 4; ++c) {
    union { uint4 u; unsigned short s[8]; } st;
    #pragma unroll
    for (int jj = 0; jj < 8; ++jj) st.s[jj] = f2bf(accv[c * 8 + jj] * inv);
    *(uint4*)&og[c * 8] = st.u;
  }
}

extern "C" void kernel_launch(void* const* d_in, const int* in_sizes, int n_in,
                              void* d_out, int out_size, void* d_ws, size_t ws_size,
                              hipStream_t stream) {
  const float* x      = (const float*)d_in[0];
  const float* w_qkv  = (const float*)d_in[1];
  const float* b_qkv  = (const float*)d_in[2];
  const float* rpb    = (const float*)d_in[3];
  const float* w_proj = (const float*)d_in[4];
  const float* b_proj = (const float*)d_in[5];
  const int* kn       = (const int*)d_in[6];
  float* out          = (float*)d_out;

  unsigned short* ws      = (unsigned short*)d_ws;
  unsigned short* wT_qkv  = ws;                              // 3072x1024 bf16
  unsigned short* wT_proj = wT_qkv + (size_t)3072 * 1024;    // 1024x1024 bf16
  unsigned short* x_bf    = wT_proj + (size_t)1024 * 1024;   // 8192x1024 bf16
  unsigned short* qkv_ws  = x_bf + (size_t)8192 * 1024;      // 3*TEN bf16
  unsigned short* attn_ws = qkv_ws + 3 * TEN;                // 8192x1024 bf16

  cvt_f32_bf16_kernel<<<(8192 * 1024) / (256 * 8), 256, 0, stream>>>(x, x_bf, 8192 * 1024);
  transpose_f32_bf16<<<dim3(3072 / 64, 1024 / 64), 256, 0, stream>>>(w_qkv, wT_qkv, 1024, 3072);
  transpose_f32_bf16<<<dim3(1024 / 64, 1024 / 64), 256, 0, stream>>>(w_proj, wT_proj, 1024, 1024);
  gemm_bt_kernel<0><<<dim3(3072 / 128, 8192 / 128), 256, 0, stream>>>(
      x_bf, wT_qkv, b_qkv, qkv_ws, nullptr, 8192, 3072, 1024, 0.125f);
  natt_kernel<<<dim3(B_ * H_, L_ / TL), 256, 0, stream>>>(qkv_ws, rpb, kn, attn_ws);
  gemm_bt_kernel<1><<<dim3(1024 / 128, 8192 / 128), 256, 0, stream>>>(
      attn_ws, wT_proj, b_proj, nullptr, out, 8192, 1024, 1024, 1.0f);
}

// Round 3
// 228.540 us; speedup vs baseline: 1.0453x; 1.0174x over previous
//
#include <hip/hip_runtime.h>
#include <hip/hip_bf16.h>
#include <stdint.h>

typedef __bf16 bf16x8 __attribute__((ext_vector_type(8)));
typedef float floatx4 __attribute__((ext_vector_type(4)));

#define B_ 2
#define L_ 4096
#define C_ 1024
#define H_ 16
#define D_ 64
constexpr size_t TEN = (size_t)B_ * H_ * L_ * D_;  // 8388608 elems per q/k/v tensor

__device__ __forceinline__ float bf2f(unsigned short u) {
  union { unsigned int i; float f; } x; x.i = ((unsigned int)u) << 16; return x.f;
}
__device__ __forceinline__ unsigned short f2bf(float f) {
  union { float f; unsigned int i; } x; x.f = f;
  unsigned int i = x.i;
  return (unsigned short)((i + 0x7FFFu + ((i >> 16) & 1u)) >> 16);
}

// direct global->LDS async copy, 16B per lane (global_load_lds_dwordx4)
__device__ __forceinline__ void async_copy16(const unsigned short* g, unsigned short* l) {
  __builtin_amdgcn_global_load_lds(
      (const __attribute__((address_space(1))) unsigned int*)g,
      (__attribute__((address_space(3))) unsigned int*)l,
      16, 0, 0);
}

// ---------------- elementwise f32 -> bf16 ----------------
__global__ __launch_bounds__(256) void cvt_f32_bf16_kernel(
    const float* __restrict__ in, unsigned short* __restrict__ out, int n) {
  int i = (blockIdx.x * 256 + threadIdx.x) * 8;
  if (i >= n) return;
  float4 a = *(const float4*)&in[i];
  float4 b = *(const float4*)&in[i + 4];
  union { uint4 u; unsigned short s[8]; } st;
  st.s[0] = f2bf(a.x); st.s[1] = f2bf(a.y); st.s[2] = f2bf(a.z); st.s[3] = f2bf(a.w);
  st.s[4] = f2bf(b.x); st.s[5] = f2bf(b.y); st.s[6] = f2bf(b.z); st.s[7] = f2bf(b.w);
  *(uint4*)&out[i] = st.u;
}

// ---------------- transpose f32 in -> bf16 out, dims divisible by 64 ----------------
__global__ __launch_bounds__(256) void transpose_f32_bf16(
    const float* __restrict__ in, unsigned short* __restrict__ out,
    int R, int Ccols) {
  __shared__ float tile[64][65];
  const int bx = blockIdx.x * 64;  // col base in input
  const int by = blockIdx.y * 64;  // row base in input
  const int t = threadIdx.x;
  for (int i = t; i < 1024; i += 256) {
    int r = i >> 4, c4 = (i & 15) << 2;
    float4 v = *(const float4*)&in[(size_t)(by + r) * Ccols + bx + c4];
    tile[r][c4] = v.x; tile[r][c4 + 1] = v.y; tile[r][c4 + 2] = v.z; tile[r][c4 + 3] = v.w;
  }
  __syncthreads();
  for (int i = t; i < 512; i += 256) {
    int r = i >> 3, c8 = (i & 7) << 3;  // r = output row (input col)
    union { uint4 u; unsigned short s[8]; } st;
    #pragma unroll
    for (int j = 0; j < 8; ++j) st.s[j] = f2bf(tile[c8 + j][r]);
    *(uint4*)&out[(size_t)(bx + r) * R + by + c8] = st.u;
  }
}

// ---------------- GEMM: A (MxK) * Bt^T (Bt NxK), bf16 MFMA, phase-pipelined ------
// BM=256, BN=128, BK=64, 512 threads = 8 waves (4M x 2N), per-wave C = 64x64.
// Triple-buffered LDS (144 KiB), global_load_lds staged ONE FULL TILE ahead,
// counted s_waitcnt vmcnt(6) once per K-tile (T3+T4), T2 both-sides XOR swizzle,
// T5 setprio around MFMA clusters. K hard-wired 1024 = 16 tiles.
// MODE 0: scatter into q/k/v (B,H,L,D) bf16 with bias + q-scale
// MODE 1: plain C = A*B + bias -> out_f (MxN f32)
template <int MODE>
__global__ __launch_bounds__(512, 2) void gemm256_kernel(
    const unsigned short* __restrict__ A, const unsigned short* __restrict__ Bt,
    const float* __restrict__ bias, unsigned short* __restrict__ out_bf,
    float* __restrict__ out_f, int M, int N, int K, float qscale) {
  constexpr int BK = 64;
  __shared__ unsigned short ash0[256 * BK], ash1[256 * BK], ash2[256 * BK];  // 32 KiB each
  __shared__ unsigned short bsh0[128 * BK], bsh1[128 * BK], bsh2[128 * BK];  // 16 KiB each

  const int t = threadIdx.x;
  // bijective XCD swizzle (nwg % 8 == 0: 768 and 256)
  const int nwgx = gridDim.x;
  const int nwg = nwgx * gridDim.y;
  const int flat = blockIdx.y * nwgx + blockIdx.x;
  const int cpx = nwg >> 3;
  const int swz = (flat & 7) * cpx + (flat >> 3);
  const int n0 = (swz % nwgx) * 128;
  const int m0 = (swz / nwgx) * 256;

  const int wave = t >> 6, lane = t & 63;
  const int wr = wave >> 1;  // 0..3 -> 64-row strip
  const int wc = wave & 1;   // 0..1 -> 64-col strip
  const int lm = lane & 15, quad = lane >> 4;

  floatx4 acc[4][4];
  #pragma unroll
  for (int i = 0; i < 4; ++i)
    #pragma unroll
    for (int j = 0; j < 4; ++j) acc[i][j] = (floatx4)0.0f;

// stage one K-tile: A 4 loads + B 2 loads per thread; LDS dest LINEAR,
// global source col pre-XOR'd so swizzled READ returns logical data (rule #21)
#define STAGE(KT, SA, SB) do { \
    _Pragma("unroll") \
    for (int q = 0; q < 4; ++q) { \
      int off = (q * 512 + t) * 8; \
      int r_ = off >> 6; \
      int c_ = (off & 63) ^ ((r_ & 7) << 3); \
      async_copy16(&A[(size_t)(m0 + r_) * K + (KT) + c_], &SA[off]); \
    } \
    _Pragma("unroll") \
    for (int q = 0; q < 2; ++q) { \
      int off = (q * 512 + t) * 8; \
      int r_ = off >> 6; \
      int c_ = (off & 63) ^ ((r_ & 7) << 3); \
      async_copy16(&Bt[(size_t)(n0 + r_) * K + (KT) + c_], &SB[off]); \
    } \
  } while (0)

// one phase: n-half NH of the wave tile over full BK=64.
// 12 ds_read_b128 -> barrier -> setprio(1) -> 16 MFMA -> setprio(0) -> TAIL -> barrier
#define PHASE(ASH, BSH, NH, TAILSTMT) do { \
    bf16x8 af[4][2], bfr[2][2]; \
    _Pragma("unroll") \
    for (int i = 0; i < 4; ++i) { \
      int ra = wr * 64 + i * 16 + lm; \
      _Pragma("unroll") \
      for (int k = 0; k < 2; ++k) \
        af[i][k] = *(const bf16x8*)&ASH[ra * 64 + ((k * 32 + quad * 8) ^ ((ra & 7) << 3))]; \
    } \
    _Pragma("unroll") \
    for (int j = 0; j < 2; ++j) { \
      int rb = wc * 64 + (NH) * 32 + j * 16 + lm; \
      _Pragma("unroll") \
      for (int k = 0; k < 2; ++k) \
        bfr[j][k] = *(const bf16x8*)&BSH[rb * 64 + ((k * 32 + quad * 8) ^ ((rb & 7) << 3))]; \
    } \
    asm volatile("" ::: "memory"); \
    __builtin_amdgcn_s_barrier(); \
    __builtin_amdgcn_s_setprio(1); \
    _Pragma("unroll") \
    for (int k = 0; k < 2; ++k) \
      _Pragma("unroll") \
      for (int i = 0; i < 4; ++i) \
        _Pragma("unroll") \
        for (int j = 0; j < 2; ++j) \
          acc[i][(NH) * 2 + j] = \
              __builtin_amdgcn_mfma_f32_16x16x32_bf16(af[i][k], bfr[j][k], acc[i][(NH) * 2 + j], 0, 0, 0); \
    __builtin_amdgcn_s_setprio(0); \
    TAILSTMT \
    asm volatile("" ::: "memory"); \
    __builtin_amdgcn_s_barrier(); \
  } while (0)

#define WAIT6 asm volatile("s_waitcnt vmcnt(6)" ::: "memory");
#define WAIT0 asm volatile("s_waitcnt vmcnt(0)" ::: "memory");

// tile T: phase 0 stages tile T+2 into the buffer freed at end of tile T-1;
// end-of-tile counted wait confirms tile T+1 (or drains in the tail).
#define TILE(KT2, ASH, BSH, SAN, SBN, DO_STAGE, TAILSTMT) do { \
    if (DO_STAGE) STAGE((KT2), SAN, SBN); \
    PHASE(ASH, BSH, 0, ;); \
    PHASE(ASH, BSH, 1, TAILSTMT); \
  } while (0)

  // prologue: stage tiles 0,1; counted wait (12 outstanding -> 6) => tile 0 landed
  STAGE(0, ash0, bsh0);
  STAGE(BK, ash1, bsh1);
  WAIT6
  asm volatile("" ::: "memory");
  __builtin_amdgcn_s_barrier();

  // tiles 0..11: buffers cycle 0,1,2; tile T stages T+2 into buf (T+2)%3
  for (int g = 0; g < 4; ++g) {
    int kb = g * 3 * BK;
    TILE(kb + 2 * BK, ash0, bsh0, ash2, bsh2, true, WAIT6);
    TILE(kb + 3 * BK, ash1, bsh1, ash0, bsh0, true, WAIT6);
    TILE(kb + 4 * BK, ash2, bsh2, ash1, bsh1, true, WAIT6);
  }
  // tiles 12..15 (K=1024): 12 stages 14, 13 stages 15, then drain
  TILE(14 * BK, ash0, bsh0, ash2, bsh2, true, WAIT6);
  TILE(15 * BK, ash1, bsh1, ash0, bsh0, true, WAIT6);
  TILE(0,       ash2, bsh2, ash0, bsh0, false, WAIT0);
  TILE(0,       ash0, bsh0, ash1, bsh1, false, ;);

#undef TILE
#undef WAIT0
#undef WAIT6
#undef PHASE
#undef STAGE

  #pragma unroll
  for (int jj = 0; jj < 4; ++jj) {
    int col = n0 + wc * 64 + jj * 16 + lm;
    float bv = bias[col];
    if (MODE == 0) {
      int which = col >> 10;
      int rem = col & 1023;
      int h = rem >> 6, d = rem & 63;
      float mul = (which == 0) ? qscale : 1.0f;
      #pragma unroll
      for (int i = 0; i < 4; ++i)
        #pragma unroll
        for (int r = 0; r < 4; ++r) {
          int row = m0 + wr * 64 + i * 16 + quad * 4 + r;
          int b = row >> 12, l = row & (L_ - 1);
          float v = (acc[i][jj][r] + bv) * mul;
          out_bf[(size_t)which * TEN + (((size_t)(b * H_ + h) * L_ + l) * D_ + d)] = f2bf(v);
        }
    } else {
      #pragma unroll
      for (int i = 0; i < 4; ++i)
        #pragma unroll
        for (int r = 0; r < 4; ++r) {
          int row = m0 + wr * 64 + i * 16 + quad * 4 + r;
          out_f[(size_t)row * N + col] = acc[i][jj][r] + bv;
        }
    }
  }
}

// ---------------- neighborhood attention, online softmax ----------------
constexpr int KKMAX = 63;
constexpr int TL = 128;
constexpr int LDK = 72;

__global__ __launch_bounds__(256) void natt_kernel(
    const unsigned short* __restrict__ qkv,  // q,k,v each TEN elems, (B,H,L,D) bf16
    const float* __restrict__ rpb,           // H x (2kk-1) f32
    const int* __restrict__ knp,
    unsigned short* __restrict__ attn_out) {  // (B*L) x C bf16
  __shared__ unsigned short k_sh[(TL + KKMAX) * LDK];
  __shared__ unsigned short v_sh[(TL + KKMAX) * LDK];
  __shared__ float rpb_sh[2 * KKMAX + 1];

  const int bh = blockIdx.x;
  const int h = bh & (H_ - 1);
  const int b = bh >> 4;
  const int l0 = blockIdx.y * TL;
  const int t = threadIdx.x;

  int kn = knp[0];
  if (kn > 65536 || kn < 0) {  // guard: value stored as float bits
    union { int i; float f; } u; u.i = kn; kn = (int)u.f;
  }
  int rr = 1;
  while ((rr + 1) * (rr + 1) <= kn) ++rr;
  int kk = rr + 1;
  if (kk > KKMAX) kk = KKMAX;

  int base = l0 - kk / 2;
  if (base < 0) base = 0;
  if (base > L_ - kk) base = L_ - kk;
  int nrows = TL + kk;
  if (nrows > L_ - base) nrows = L_ - base;

  const unsigned short* kg = qkv + TEN + (size_t)bh * L_ * D_;
  const unsigned short* vg = qkv + 2 * TEN + (size_t)bh * L_ * D_;

  for (int i = t; i < nrows * 8; i += 256) {
    int row = i >> 3, c8 = (i & 7) << 3;
    uint4 kv = *(const uint4*)&kg[(size_t)(base + row) * D_ + c8];
    *(uint4*)&k_sh[row * LDK + c8] = kv;
    uint4 vv = *(const uint4*)&vg[(size_t)(base + row) * D_ + c8];
    *(uint4*)&v_sh[row * LDK + c8] = vv;
  }
  int nb = 2 * kk - 1;
  for (int i = t; i < nb; i += 256) rpb_sh[i] = rpb[h * nb + i];
  __syncthreads();

  const int qi = t >> 1, half = t & 1;
  const int l = l0 + qi;

  const unsigned short* qg = qkv + (size_t)bh * L_ * D_ + (size_t)l * D_ + half * 32;
  float qv[32];
  #pragma unroll
  for (int c = 0; c < 4; ++c) {
    union { uint4 u; unsigned short s[8]; } ld;
    ld.u = *(const uint4*)&qg[c * 8];
    #pragma unroll
    for (int j = 0; j < 8; ++j) qv[c * 8 + j] = bf2f(ld.s[j]);
  }

  int start = l - kk / 2;
  if (start < 0) start = 0;
  if (start > L_ - kk) start = L_ - kk;
  const int srow = start - base;
  const int boff = start - l + kk - 1;

  float m = -1e30f, lsum = 0.0f;
  float accv[32];
  #pragma unroll
  for (int d = 0; d < 32; ++d) accv[d] = 0.0f;

  for (int j = 0; j < kk; ++j) {
    const unsigned short* kr = &k_sh[(srow + j) * LDK + half * 32];
    float partial = 0.0f;
    #pragma unroll
    for (int c = 0; c < 4; ++c) {
      union { uint4 u; unsigned short s[8]; } ld;
      ld.u = *(const uint4*)&kr[c * 8];
      #pragma unroll
      for (int jj = 0; jj < 8; ++jj) partial += qv[c * 8 + jj] * bf2f(ld.s[jj]);
    }
    float s = partial + __shfl_xor(partial, 1) + rpb_sh[boff + j];
    float p;
    if (s > m) {
      float corr = __expf(m - s);
      lsum *= corr;
      #pragma unroll
      for (int d = 0; d < 32; ++d) accv[d] *= corr;
      m = s;
      p = 1.0f;
    } else {
      p = __expf(s - m);
    }
    lsum += p;
    const unsigned short* vr = &v_sh[(srow + j) * LDK + half * 32];
    #pragma unroll
    for (int c = 0; c < 4; ++c) {
      union { uint4 u; unsigned short s[8]; } ld;
      ld.u = *(const uint4*)&vr[c * 8];
      #pragma unroll
      for (int jj = 0; jj < 8; ++jj) accv[c * 8 + jj] += p * bf2f(ld.s[jj]);
    }
  }
  float inv = 1.0f / lsum;
  unsigned short* og = attn_out + ((size_t)(b * L_ + l) * C_ + h * D_ + half * 32);
  #pragma unroll
  for (int c = 0; c < 4; ++c) {
    union { uint4 u; unsigned short s[8]; } st;
    #pragma unroll
    for (int jj = 0; jj < 8; ++jj) st.s[jj] = f2bf(accv[c * 8 + jj] * inv);
    *(uint4*)&og[c * 8] = st.u;
  }
}

extern "C" void kernel_launch(void* const* d_in, const int* in_sizes, int n_in,
                              void* d_out, int out_size, void* d_ws, size_t ws_size,
                              hipStream_t stream) {
  const float* x      = (const float*)d_in[0];
  const float* w_qkv  = (const float*)d_in[1];
  const float* b_qkv  = (const float*)d_in[2];
  const float* rpb    = (const float*)d_in[3];
  const float* w_proj = (const float*)d_in[4];
  const float* b_proj = (const float*)d_in[5];
  const int* kn       = (const int*)d_in[6];
  float* out          = (float*)d_out;

  unsigned short* ws      = (unsigned short*)d_ws;
  unsigned short* wT_qkv  = ws;                              // 3072x1024 bf16
  unsigned short* wT_proj = wT_qkv + (size_t)3072 * 1024;    // 1024x1024 bf16
  unsigned short* x_bf    = wT_proj + (size_t)1024 * 1024;   // 8192x1024 bf16
  unsigned short* qkv_ws  = x_bf + (size_t)8192 * 1024;      // 3*TEN bf16
  unsigned short* attn_ws = qkv_ws + 3 * TEN;                // 8192x1024 bf16

  cvt_f32_bf16_kernel<<<(8192 * 1024) / (256 * 8), 256, 0, stream>>>(x, x_bf, 8192 * 1024);
  transpose_f32_bf16<<<dim3(3072 / 64, 1024 / 64), 256, 0, stream>>>(w_qkv, wT_qkv, 1024, 3072);
  transpose_f32_bf16<<<dim3(1024 / 64, 1024 / 64), 256, 0, stream>>>(w_proj, wT_proj, 1024, 1024);
  gemm256_kernel<0><<<dim3(3072 / 128, 8192 / 256), 512, 0, stream>>>(
      x_bf, wT_qkv, b_qkv, qkv_ws, nullptr, 8192, 3072, 1024, 0.125f);
  natt_kernel<<<dim3(B_ * H_, L_ / TL), 256, 0, stream>>>(qkv_ws, rpb, kn, attn_ws);
  gemm256_kernel<1><<<dim3(1024 / 128, 8192 / 256), 512, 0, stream>>>(
      attn_ws, wT_proj, b_proj, nullptr, out, 8192, 1024, 1024, 1.0f);
}